// Round 7
// baseline (300.721 us; speedup 1.0000x reference)
//
#include <hip/hip_runtime.h>
#include <hip/hip_bf16.h>
#include <stdint.h>

#define BSZ 1024
#define KF 32768            // feature length (elements == bytes in fp8)
#define SPLITK 32
#define KPER (KF / SPLITK)  // 1024
#define BKB 128             // K bytes staged per iter
#define TEMP_INV 10.0f

typedef float f32x4 __attribute__((ext_vector_type(4)));
typedef int v8i __attribute__((ext_vector_type(8)));

__device__ __forceinline__ void async_copy16(const void* g, void* l) {
    __builtin_amdgcn_global_load_lds(
        (const __attribute__((address_space(1))) void*)g,
        (__attribute__((address_space(3))) void*)l, 16, 0, 0);
}

__device__ __forceinline__ float waveSum(float v) {
    for (int o = 32; o > 0; o >>= 1) v += __shfl_down(v, o);
    return v;
}
__device__ __forceinline__ float waveMax(float v) {
    for (int o = 32; o > 0; o >>= 1) v = fmaxf(v, __shfl_down(v, o));
    return v;
}
__device__ __forceinline__ float blockSum(float v, float* red, int tid) {
    v = waveSum(v);
    __syncthreads();
    if ((tid & 63) == 0) red[tid >> 6] = v;
    __syncthreads();
    return red[0] + red[1] + red[2] + red[3];
}
__device__ __forceinline__ float blockMax(float v, float* red, int tid) {
    v = waveMax(v);
    __syncthreads();
    if ((tid & 63) == 0) red[tid >> 6] = v;
    __syncthreads();
    return fmaxf(fmaxf(red[0], red[1]), fmaxf(red[2], red[3]));
}

// K1: per-row sum of squares (fp32, exact) + fp32->fp8(e4m3) convert.
// Block 0 also zeroes the global accumulators used by k_loss_rows (stream-ordered).
__global__ __launch_bounds__(256) void k_norm_convert(
    const float* __restrict__ f, unsigned char* __restrict__ f8,
    float* __restrict__ inv_norm, float* __restrict__ gaccum) {
    int row = blockIdx.x, tid = threadIdx.x;
    if (row == 0 && tid < 4) gaccum[tid] = 0.f;   // loss,valid,corr,ticket(int 0)
    const float4* src = (const float4*)(f + (size_t)row * KF);
    int4* dst = (int4*)(f8 + (size_t)row * KF);
    float ss = 0.f;
    for (int o = 0; o < 8; ++o) {
        int base4 = o * 1024 + tid * 4;
        int4 pk;
        int* pkp = &pk.x;
#pragma unroll
        for (int q = 0; q < 4; ++q) {
            float4 v = src[base4 + q];
            ss += v.x * v.x + v.y * v.y + v.z * v.z + v.w * v.w;
            int wd = __builtin_amdgcn_cvt_pk_fp8_f32(v.x, v.y, 0, false);
            wd = __builtin_amdgcn_cvt_pk_fp8_f32(v.z, v.w, wd, true);
            pkp[q] = wd;
        }
        dst[o * 256 + tid] = pk;
    }
    __shared__ float red[4];
    float tot = blockSum(ss, red, tid);
    if (tid == 0) inv_norm[row] = 1.0f / fmaxf(sqrtf(tot), 1e-8f);
}

// K2: MX-fp8 (unit scales) gram partials, symmetric tiles (bi>=bj), mirrored
// epilogue, fp8 e4m3 partial output (|partial|<=~183 << 448; diag saturates
// but is masked downstream). K-loop identical to R5 (best so far).
__global__ __launch_bounds__(256) void k_gemm(
    const unsigned char* __restrict__ f8, unsigned char* __restrict__ partials) {
    __shared__ unsigned char Alds[128 * BKB];   // 16 KB
    __shared__ unsigned char Blds[128 * BKB];   // 16 KB
    int tid = threadIdx.x;

    int t = blockIdx.x;                 // triangular tile: bi >= bj
    int bi = 0, accu = 0;
    while (accu + bi + 1 <= t) { accu += bi + 1; ++bi; }
    int bj = t - accu;
    int row0 = bi * 128, col0 = bj * 128;
    int p = blockIdx.y;
    size_t kbase = (size_t)p * KPER;

    const unsigned char* Ag = f8 + (size_t)row0 * KF;
    const unsigned char* Bg = f8 + (size_t)col0 * KF;
    int lane = tid & 63, w = tid >> 6;
    int wrow = (w >> 1) * 64, wcol = (w & 1) * 64;
    int mrow = lane & 15, quad = lane >> 4;

    // staging: 1024 chunks of 16B per matrix; LDS slot s of row r holds
    // global chunk s^(r&7)  (XOR swizzle -> 2-way banks on read = free)
    int r_st[4], g_st[4];
#pragma unroll
    for (int c = 0; c < 4; ++c) {
        int idx = c * 256 + tid;
        r_st[c] = idx >> 3;
        g_st[c] = (idx & 7) ^ (r_st[c] & 7);
    }

    f32x4 acc[4][4] = {};

    for (int kt = 0; kt < KPER / BKB; ++kt) {   // 8 iters
        size_t k0 = kbase + (size_t)kt * BKB;
        __syncthreads();
#pragma unroll
        for (int c = 0; c < 4; ++c) {
            int idx = c * 256 + tid;
            async_copy16(Ag + (size_t)r_st[c] * KF + k0 + g_st[c] * 16, &Alds[idx * 16]);
            async_copy16(Bg + (size_t)r_st[c] * KF + k0 + g_st[c] * 16, &Blds[idx * 16]);
        }
        __syncthreads();
        // fragments: lane covers k = quad*32..quad*32+32 (chunks 2q, 2q+1);
        // identical k-mapping on A and B => gram correct under any shared perm.
        v8i a8[4], b8[4];
#pragma unroll
        for (int mi = 0; mi < 4; ++mi) {
            int rA = wrow + mi * 16 + mrow;
            int4 lo = *(const int4*)&Alds[rA * BKB + ((quad * 2)     ^ (rA & 7)) * 16];
            int4 hi = *(const int4*)&Alds[rA * BKB + ((quad * 2 + 1) ^ (rA & 7)) * 16];
            a8[mi] = (v8i){lo.x, lo.y, lo.z, lo.w, hi.x, hi.y, hi.z, hi.w};
        }
#pragma unroll
        for (int ni = 0; ni < 4; ++ni) {
            int rB = wcol + ni * 16 + mrow;
            int4 lo = *(const int4*)&Blds[rB * BKB + ((quad * 2)     ^ (rB & 7)) * 16];
            int4 hi = *(const int4*)&Blds[rB * BKB + ((quad * 2 + 1) ^ (rB & 7)) * 16];
            b8[ni] = (v8i){lo.x, lo.y, lo.z, lo.w, hi.x, hi.y, hi.z, hi.w};
        }
#pragma unroll
        for (int mi = 0; mi < 4; ++mi)
#pragma unroll
            for (int ni = 0; ni < 4; ++ni)
                acc[mi][ni] = __builtin_amdgcn_mfma_scale_f32_16x16x128_f8f6f4(
                    a8[mi], b8[ni], acc[mi][ni],
                    0, 0,                     // cbsz/blgp = fp8(e4m3)
                    0, 0x7F7F7F7F,            // A scales: E8M0 127 -> 2^0 (exact)
                    0, 0x7F7F7F7F);           // B scales: unit
    }

    unsigned char* outp = partials + (size_t)p * BSZ * BSZ;
#pragma unroll
    for (int mi = 0; mi < 4; ++mi)
#pragma unroll
        for (int ni = 0; ni < 4; ++ni)
#pragma unroll
            for (int r = 0; r < 4; ++r) {
                int row = row0 + wrow + mi * 16 + quad * 4 + r;   // C/D: row=(lane>>4)*4+reg
                int col = col0 + wcol + ni * 16 + mrow;           //      col=lane&15
                int b = __builtin_amdgcn_cvt_pk_fp8_f32(
                            acc[mi][ni][r], acc[mi][ni][r], 0, false);
                outp[(size_t)row * BSZ + col] = (unsigned char)(b & 0xFF);
            }
    if (bi != bj) {
#pragma unroll
        for (int mi = 0; mi < 4; ++mi)
#pragma unroll
            for (int ni = 0; ni < 4; ++ni) {
                int rowm = col0 + wcol + ni * 16 + mrow;
                int colm = row0 + wrow + mi * 16 + quad * 4;   // 4-aligned
                int pk = __builtin_amdgcn_cvt_pk_fp8_f32(
                             acc[mi][ni][0], acc[mi][ni][1], 0, false);
                pk = __builtin_amdgcn_cvt_pk_fp8_f32(
                         acc[mi][ni][2], acc[mi][ni][3], pk, true);
                *(int*)&outp[(size_t)rowm * BSZ + colm] = pk;
            }
    }
}

// K3: per-row loss, single pass (fixed shift 10: scores<=10 analytically),
// fused final reduce via device-scope atomics + ticket.
__global__ __launch_bounds__(256) void k_loss_rows(
    const unsigned char* __restrict__ partials, const float* __restrict__ inv_norm,
    const int* __restrict__ labels, float* __restrict__ gaccum,
    float* __restrict__ out) {
    int i = blockIdx.x, tid = threadIdx.x;
    __shared__ int slab[BSZ];
    __shared__ float red[4];
    __shared__ int s_ticket;
    for (int c = 0; c < 4; ++c) slab[c * 256 + tid] = labels[c * 256 + tid];
    float inv_i = inv_norm[i];

    int j4 = tid * 4;
    float sx = 0.f, sy = 0.f, sz = 0.f, sw = 0.f;
#pragma unroll
    for (int p2 = 0; p2 < SPLITK; ++p2) {
        int v = *(const int*)&partials[(size_t)p2 * BSZ * BSZ + (size_t)i * BSZ + j4];
        sx += __builtin_amdgcn_cvt_f32_fp8(v, 0);
        sy += __builtin_amdgcn_cvt_f32_fp8(v, 1);
        sz += __builtin_amdgcn_cvt_f32_fp8(v, 2);
        sw += __builtin_amdgcn_cvt_f32_fp8(v, 3);
    }
    float4 invj = *(const float4*)&inv_norm[j4];
    float s4[4];
    s4[0] = sx * inv_i * invj.x * TEMP_INV;
    s4[1] = sy * inv_i * invj.y * TEMP_INV;
    s4[2] = sz * inv_i * invj.z * TEMP_INV;
    s4[3] = sw * inv_i * invj.w * TEMP_INV;
    __syncthreads();

    int lab_i = slab[i];
    float pos_sum = 0.f, neg_sum = 0.f, mp = -3.0e38f, mn = -3.0e38f;
#pragma unroll
    for (int q = 0; q < 4; ++q) {
        int j = j4 + q;
        if (j == i) continue;
        float s = s4[q];
        float e = __expf(s - 10.0f);           // s<=10+eps -> e in (0,1]
        if (slab[j] == lab_i) { pos_sum += e; mp = fmaxf(mp, s); }
        else                  { neg_sum += e; mn = fmaxf(mn, s); }
    }
    float ps = blockSum(pos_sum, red, tid);
    float ns = blockSum(neg_sum, red, tid);
    float mpa = blockMax(mp, red, tid);
    float mna = blockMax(mn, red, tid);

    if (tid == 0) {
        bool valid = (mpa > -1.0e37f) && (mna > -1.0e37f);
        float li = valid ? (logf(ns) - logf(ps)) : 0.f;
        atomicAdd(&gaccum[0], li);
        atomicAdd(&gaccum[1], valid ? 1.f : 0.f);
        atomicAdd(&gaccum[2], (valid && (mpa > mna)) ? 1.f : 0.f);
        __threadfence();
        s_ticket = atomicAdd((int*)&gaccum[3], 1);
    }
    __syncthreads();
    if (s_ticket == BSZ - 1 && tid == 0) {
        float sl = atomicAdd(&gaccum[0], 0.f);   // device-scope coherent read
        float sv = atomicAdd(&gaccum[1], 0.f);
        float sc = atomicAdd(&gaccum[2], 0.f);
        out[0] = (sv > 0.f) ? sl / fmaxf(sv, 1.f) : 0.f;
        out[1] = (sv > 0.f) ? sc / fmaxf(sv, 1.f) : 0.5f;
    }
}

extern "C" void kernel_launch(void* const* d_in, const int* in_sizes, int n_in,
                              void* d_out, int out_size, void* d_ws, size_t ws_size,
                              hipStream_t stream) {
    const float* feats = (const float*)d_in[0];
    const int* labels = (const int*)d_in[1];
    float* out = (float*)d_out;
    char* ws = (char*)d_ws;

    // ws: [0,32MB) fp8 features | [32MB,64MB) 32 fp8 gram partials | small arrays
    unsigned char* f8       = (unsigned char*)ws;
    unsigned char* partials = (unsigned char*)(ws + (size_t)32 * 1024 * 1024);
    float* inv_norm         = (float*)(ws + (size_t)64 * 1024 * 1024);
    float* gaccum           = inv_norm + BSZ;   // loss,valid,corr,ticket

    k_norm_convert<<<BSZ, 256, 0, stream>>>(feats, f8, inv_norm, gaccum);
    k_gemm<<<dim3(36, SPLITK), 256, 0, stream>>>(f8, partials);
    k_loss_rows<<<BSZ, 256, 0, stream>>>(partials, inv_norm, labels, gaccum, out);
}

// Round 8
// 268.168 us; speedup vs baseline: 1.1214x; 1.1214x over previous
//
#include <hip/hip_runtime.h>
#include <hip/hip_bf16.h>
#include <stdint.h>

#define BSZ 1024
#define KF 32768            // feature length (elements == bytes in fp8)
#define SPLITK 32
#define KPER (KF / SPLITK)  // 1024
#define BKB 128             // K bytes staged per iter
#define TEMP_INV 10.0f

typedef float f32x4 __attribute__((ext_vector_type(4)));
typedef int v8i __attribute__((ext_vector_type(8)));

__device__ __forceinline__ void async_copy16(const void* g, void* l) {
    __builtin_amdgcn_global_load_lds(
        (const __attribute__((address_space(1))) void*)g,
        (__attribute__((address_space(3))) void*)l, 16, 0, 0);
}

__device__ __forceinline__ unsigned short f2bf_bits(float x) {
    union { float f; uint32_t u; } t; t.f = x;
    uint32_t r = t.u + 0x7FFFu + ((t.u >> 16) & 1u);   // RN-even, finite inputs
    return (unsigned short)(r >> 16);
}
__device__ __forceinline__ float bf2f(unsigned short b) {
    union { uint32_t u; float f; } t; t.u = ((uint32_t)b) << 16; return t.f;
}

__device__ __forceinline__ float waveSum(float v) {
    for (int o = 32; o > 0; o >>= 1) v += __shfl_down(v, o);
    return v;
}
__device__ __forceinline__ float waveMax(float v) {
    for (int o = 32; o > 0; o >>= 1) v = fmaxf(v, __shfl_down(v, o));
    return v;
}
__device__ __forceinline__ float blockSum(float v, float* red, int tid) {
    v = waveSum(v);
    __syncthreads();
    if ((tid & 63) == 0) red[tid >> 6] = v;
    __syncthreads();
    return red[0] + red[1] + red[2] + red[3];
}
__device__ __forceinline__ float blockMax(float v, float* red, int tid) {
    v = waveMax(v);
    __syncthreads();
    if ((tid & 63) == 0) red[tid >> 6] = v;
    __syncthreads();
    return fmaxf(fmaxf(red[0], red[1]), fmaxf(red[2], red[3]));
}

// K1: per-row sum of squares (fp32, exact) + fp32->fp8(e4m3) convert.
__global__ __launch_bounds__(256) void k_norm_convert(
    const float* __restrict__ f, unsigned char* __restrict__ f8,
    float* __restrict__ inv_norm) {
    int row = blockIdx.x, tid = threadIdx.x;
    const float4* src = (const float4*)(f + (size_t)row * KF);
    int4* dst = (int4*)(f8 + (size_t)row * KF);
    float ss = 0.f;
    for (int o = 0; o < 8; ++o) {
        int base4 = o * 1024 + tid * 4;
        int4 pk;
        int* pkp = &pk.x;
#pragma unroll
        for (int q = 0; q < 4; ++q) {
            float4 v = src[base4 + q];
            ss += v.x * v.x + v.y * v.y + v.z * v.z + v.w * v.w;
            int wd = __builtin_amdgcn_cvt_pk_fp8_f32(v.x, v.y, 0, false);
            wd = __builtin_amdgcn_cvt_pk_fp8_f32(v.z, v.w, wd, true);
            pkp[q] = wd;
        }
        dst[o * 256 + tid] = pk;
    }
    __shared__ float red[4];
    float tot = blockSum(ss, red, tid);
    if (tid == 0) inv_norm[row] = 1.0f / fmaxf(sqrtf(tot), 1e-8f);
}

// K2: MX-fp8 (unit scales) gram partials, symmetric tiles (bi>=bj), mirrored
// epilogue, bf16 partial output. Identical to R5 (best config).
__global__ __launch_bounds__(256) void k_gemm(
    const unsigned char* __restrict__ f8, unsigned short* __restrict__ partials) {
    __shared__ unsigned char Alds[128 * BKB];   // 16 KB
    __shared__ unsigned char Blds[128 * BKB];   // 16 KB
    int tid = threadIdx.x;

    int t = blockIdx.x;                 // triangular tile: bi >= bj
    int bi = 0, accu = 0;
    while (accu + bi + 1 <= t) { accu += bi + 1; ++bi; }
    int bj = t - accu;
    int row0 = bi * 128, col0 = bj * 128;
    int p = blockIdx.y;
    size_t kbase = (size_t)p * KPER;

    const unsigned char* Ag = f8 + (size_t)row0 * KF;
    const unsigned char* Bg = f8 + (size_t)col0 * KF;
    int lane = tid & 63, w = tid >> 6;
    int wrow = (w >> 1) * 64, wcol = (w & 1) * 64;
    int mrow = lane & 15, quad = lane >> 4;

    // staging: 1024 chunks of 16B per matrix; LDS slot s of row r holds
    // global chunk s^(r&7)  (XOR swizzle -> 2-way banks on read = free)
    int r_st[4], g_st[4];
#pragma unroll
    for (int c = 0; c < 4; ++c) {
        int idx = c * 256 + tid;
        r_st[c] = idx >> 3;
        g_st[c] = (idx & 7) ^ (r_st[c] & 7);
    }

    f32x4 acc[4][4] = {};

    for (int kt = 0; kt < KPER / BKB; ++kt) {   // 8 iters
        size_t k0 = kbase + (size_t)kt * BKB;
        __syncthreads();
#pragma unroll
        for (int c = 0; c < 4; ++c) {
            int idx = c * 256 + tid;
            async_copy16(Ag + (size_t)r_st[c] * KF + k0 + g_st[c] * 16, &Alds[idx * 16]);
            async_copy16(Bg + (size_t)r_st[c] * KF + k0 + g_st[c] * 16, &Blds[idx * 16]);
        }
        __syncthreads();
        // fragments: lane covers k = quad*32..quad*32+32 (chunks 2q, 2q+1);
        // identical k-mapping on A and B => gram correct under any shared perm.
        v8i a8[4], b8[4];
#pragma unroll
        for (int mi = 0; mi < 4; ++mi) {
            int rA = wrow + mi * 16 + mrow;
            int4 lo = *(const int4*)&Alds[rA * BKB + ((quad * 2)     ^ (rA & 7)) * 16];
            int4 hi = *(const int4*)&Alds[rA * BKB + ((quad * 2 + 1) ^ (rA & 7)) * 16];
            a8[mi] = (v8i){lo.x, lo.y, lo.z, lo.w, hi.x, hi.y, hi.z, hi.w};
        }
#pragma unroll
        for (int ni = 0; ni < 4; ++ni) {
            int rB = wcol + ni * 16 + mrow;
            int4 lo = *(const int4*)&Blds[rB * BKB + ((quad * 2)     ^ (rB & 7)) * 16];
            int4 hi = *(const int4*)&Blds[rB * BKB + ((quad * 2 + 1) ^ (rB & 7)) * 16];
            b8[ni] = (v8i){lo.x, lo.y, lo.z, lo.w, hi.x, hi.y, hi.z, hi.w};
        }
#pragma unroll
        for (int mi = 0; mi < 4; ++mi)
#pragma unroll
            for (int ni = 0; ni < 4; ++ni)
                acc[mi][ni] = __builtin_amdgcn_mfma_scale_f32_16x16x128_f8f6f4(
                    a8[mi], b8[ni], acc[mi][ni],
                    0, 0,                     // cbsz/blgp = fp8(e4m3)
                    0, 0x7F7F7F7F,            // A scales: E8M0 127 -> 2^0 (exact)
                    0, 0x7F7F7F7F);           // B scales: unit
    }

    unsigned short* outp = partials + (size_t)p * BSZ * BSZ;
#pragma unroll
    for (int mi = 0; mi < 4; ++mi)
#pragma unroll
        for (int ni = 0; ni < 4; ++ni)
#pragma unroll
            for (int r = 0; r < 4; ++r) {
                int row = row0 + wrow + mi * 16 + quad * 4 + r;   // C/D: row=(lane>>4)*4+reg
                int col = col0 + wcol + ni * 16 + mrow;           //      col=lane&15
                outp[(size_t)row * BSZ + col] = f2bf_bits(acc[mi][ni][r]);
            }
    if (bi != bj) {
#pragma unroll
        for (int mi = 0; mi < 4; ++mi)
#pragma unroll
            for (int ni = 0; ni < 4; ++ni) {
                int rowm = col0 + wcol + ni * 16 + mrow;
                int colm = row0 + wrow + mi * 16 + quad * 4;
                ushort4 v;
                v.x = f2bf_bits(acc[mi][ni][0]);
                v.y = f2bf_bits(acc[mi][ni][1]);
                v.z = f2bf_bits(acc[mi][ni][2]);
                v.w = f2bf_bits(acc[mi][ni][3]);
                *(ushort4*)&outp[(size_t)rowm * BSZ + colm] = v;
            }
    }
}

// K3: per-row loss, single pass. Scores <= 10 analytically (cosine/T), so use
// constant shift 10 (loss is shift-invariant); no srow/slab LDS staging.
__global__ __launch_bounds__(256) void k_loss_rows(
    const unsigned short* __restrict__ partials, const float* __restrict__ inv_norm,
    const int* __restrict__ labels, float* __restrict__ rloss,
    float* __restrict__ rvalid, float* __restrict__ rcorr) {
    int i = blockIdx.x, tid = threadIdx.x;
    __shared__ float red[4];
    float inv_i = inv_norm[i];
    int lab_i = labels[i];

    int j4 = tid * 4;
    float sx = 0.f, sy = 0.f, sz = 0.f, sw = 0.f;
#pragma unroll
    for (int p2 = 0; p2 < SPLITK; ++p2) {
        ushort4 v = *(const ushort4*)&partials[(size_t)p2 * BSZ * BSZ + (size_t)i * BSZ + j4];
        sx += bf2f(v.x); sy += bf2f(v.y); sz += bf2f(v.z); sw += bf2f(v.w);
    }
    float4 invj = *(const float4*)&inv_norm[j4];
    float s4[4];
    s4[0] = sx * inv_i * invj.x * TEMP_INV;
    s4[1] = sy * inv_i * invj.y * TEMP_INV;
    s4[2] = sz * inv_i * invj.z * TEMP_INV;
    s4[3] = sw * inv_i * invj.w * TEMP_INV;
    int4 labj = *(const int4*)&labels[j4];
    const int* labjp = &labj.x;

    float pos_sum = 0.f, neg_sum = 0.f, mp = -3.0e38f, mn = -3.0e38f;
#pragma unroll
    for (int q = 0; q < 4; ++q) {
        int j = j4 + q;
        if (j == i) continue;
        float s = s4[q];
        float e = __expf(s - 10.0f);           // s <= 10+eps -> e in (0,~1]
        if (labjp[q] == lab_i) { pos_sum += e; mp = fmaxf(mp, s); }
        else                   { neg_sum += e; mn = fmaxf(mn, s); }
    }
    float ps = blockSum(pos_sum, red, tid);
    float ns = blockSum(neg_sum, red, tid);
    float mpa = blockMax(mp, red, tid);
    float mna = blockMax(mn, red, tid);
    if (tid == 0) {
        bool valid = (mpa > -1.0e37f) && (mna > -1.0e37f);
        rloss[i]  = valid ? (logf(ns) - logf(ps)) : 0.f;
        rvalid[i] = valid ? 1.f : 0.f;
        rcorr[i]  = (valid && (mpa > mna)) ? 1.f : 0.f;
    }
}

// K4: final scalar reduce -> d_out[0]=loss, d_out[1]=accuracy
__global__ __launch_bounds__(256) void k_final(
    const float* __restrict__ rloss, const float* __restrict__ rvalid,
    const float* __restrict__ rcorr, float* __restrict__ out) {
    __shared__ float red[4];
    int tid = threadIdx.x;
    float sl = 0.f, sv = 0.f, sc = 0.f;
    for (int c = 0; c < 4; ++c) {
        int j = c * 256 + tid;
        sl += rloss[j]; sv += rvalid[j]; sc += rcorr[j];
    }
    sl = blockSum(sl, red, tid);
    sv = blockSum(sv, red, tid);
    sc = blockSum(sc, red, tid);
    if (tid == 0) {
        out[0] = (sv > 0.f) ? sl / fmaxf(sv, 1.f) : 0.f;
        out[1] = (sv > 0.f) ? sc / fmaxf(sv, 1.f) : 0.5f;
    }
}

extern "C" void kernel_launch(void* const* d_in, const int* in_sizes, int n_in,
                              void* d_out, int out_size, void* d_ws, size_t ws_size,
                              hipStream_t stream) {
    const float* feats = (const float*)d_in[0];
    const int* labels = (const int*)d_in[1];
    float* out = (float*)d_out;
    char* ws = (char*)d_ws;

    // ws: [0,32MB) fp8 features | [32MB,96MB) 32 bf16 gram partials | small arrays
    unsigned char* f8        = (unsigned char*)ws;
    unsigned short* partials = (unsigned short*)(ws + (size_t)32 * 1024 * 1024);
    float* inv_norm          = (float*)(ws + (size_t)96 * 1024 * 1024);
    float* rloss             = inv_norm + BSZ;
    float* rvalid            = rloss + BSZ;
    float* rcorr             = rvalid + BSZ;

    k_norm_convert<<<BSZ, 256, 0, stream>>>(feats, f8, inv_norm);
    k_gemm<<<dim3(36, SPLITK), 256, 0, stream>>>(f8, partials);
    k_loss_rows<<<BSZ, 256, 0, stream>>>(partials, inv_norm, labels, rloss, rvalid, rcorr);
    k_final<<<1, 256, 0, stream>>>(rloss, rvalid, rcorr, out);
}

// Round 9
// 252.636 us; speedup vs baseline: 1.1903x; 1.0615x over previous
//
#include <hip/hip_runtime.h>
#include <hip/hip_bf16.h>
#include <stdint.h>

#define BSZ 1024
#define KF 32768            // feature length (elements == bytes in fp8)
#define SPLITK 32
#define KPER (KF / SPLITK)  // 1024
#define BKB 128             // K bytes staged per iter
#define TEMP_INV 10.0f

typedef float f32x4 __attribute__((ext_vector_type(4)));
typedef int v8i __attribute__((ext_vector_type(8)));

__device__ __forceinline__ void async_copy16(const void* g, void* l) {
    __builtin_amdgcn_global_load_lds(
        (const __attribute__((address_space(1))) void*)g,
        (__attribute__((address_space(3))) void*)l, 16, 0, 0);
}

__device__ __forceinline__ float waveSum(float v) {
    for (int o = 32; o > 0; o >>= 1) v += __shfl_down(v, o);
    return v;
}
__device__ __forceinline__ float waveMax(float v) {
    for (int o = 32; o > 0; o >>= 1) v = fmaxf(v, __shfl_down(v, o));
    return v;
}
__device__ __forceinline__ float blockSum(float v, float* red, int tid) {
    v = waveSum(v);
    __syncthreads();
    if ((tid & 63) == 0) red[tid >> 6] = v;
    __syncthreads();
    return red[0] + red[1] + red[2] + red[3];
}
__device__ __forceinline__ float blockMax(float v, float* red, int tid) {
    v = waveMax(v);
    __syncthreads();
    if ((tid & 63) == 0) red[tid >> 6] = v;
    __syncthreads();
    return fmaxf(fmaxf(red[0], red[1]), fmaxf(red[2], red[3]));
}

// K1: per-row sum of squares (fp32, exact) + fp32->fp8(e4m3) convert.
__global__ __launch_bounds__(256) void k_norm_convert(
    const float* __restrict__ f, unsigned char* __restrict__ f8,
    float* __restrict__ inv_norm) {
    int row = blockIdx.x, tid = threadIdx.x;
    const float4* src = (const float4*)(f + (size_t)row * KF);
    int4* dst = (int4*)(f8 + (size_t)row * KF);
    float ss = 0.f;
    for (int o = 0; o < 8; ++o) {
        int base4 = o * 1024 + tid * 4;
        int4 pk;
        int* pkp = &pk.x;
#pragma unroll
        for (int q = 0; q < 4; ++q) {
            float4 v = src[base4 + q];
            ss += v.x * v.x + v.y * v.y + v.z * v.z + v.w * v.w;
            int wd = __builtin_amdgcn_cvt_pk_fp8_f32(v.x, v.y, 0, false);
            wd = __builtin_amdgcn_cvt_pk_fp8_f32(v.z, v.w, wd, true);
            pkp[q] = wd;
        }
        dst[o * 256 + tid] = pk;
    }
    __shared__ float red[4];
    float tot = blockSum(ss, red, tid);
    if (tid == 0) inv_norm[row] = 1.0f / fmaxf(sqrtf(tot), 1e-8f);
}

// K2: MX-fp8 (unit scales) gram partials, symmetric tiles (bi>=bj), mirrored
// epilogue. K-loop identical to R5/R7 (best). fp8 e4m3 partial output
// (|off-diag partial| <= ~160 << 448; diag saturates but is masked by j==i).
__global__ __launch_bounds__(256) void k_gemm(
    const unsigned char* __restrict__ f8, unsigned char* __restrict__ partials) {
    __shared__ unsigned char Alds[128 * BKB];   // 16 KB
    __shared__ unsigned char Blds[128 * BKB];   // 16 KB
    int tid = threadIdx.x;

    int t = blockIdx.x;                 // triangular tile: bi >= bj
    int bi = 0, accu = 0;
    while (accu + bi + 1 <= t) { accu += bi + 1; ++bi; }
    int bj = t - accu;
    int row0 = bi * 128, col0 = bj * 128;
    int p = blockIdx.y;
    size_t kbase = (size_t)p * KPER;

    const unsigned char* Ag = f8 + (size_t)row0 * KF;
    const unsigned char* Bg = f8 + (size_t)col0 * KF;
    int lane = tid & 63, w = tid >> 6;
    int wrow = (w >> 1) * 64, wcol = (w & 1) * 64;
    int mrow = lane & 15, quad = lane >> 4;

    // staging: 1024 chunks of 16B per matrix; LDS slot s of row r holds
    // global chunk s^(r&7)  (XOR swizzle -> 2-way banks on read = free)
    int r_st[4], g_st[4];
#pragma unroll
    for (int c = 0; c < 4; ++c) {
        int idx = c * 256 + tid;
        r_st[c] = idx >> 3;
        g_st[c] = (idx & 7) ^ (r_st[c] & 7);
    }

    f32x4 acc[4][4] = {};

    for (int kt = 0; kt < KPER / BKB; ++kt) {   // 8 iters
        size_t k0 = kbase + (size_t)kt * BKB;
        __syncthreads();
#pragma unroll
        for (int c = 0; c < 4; ++c) {
            int idx = c * 256 + tid;
            async_copy16(Ag + (size_t)r_st[c] * KF + k0 + g_st[c] * 16, &Alds[idx * 16]);
            async_copy16(Bg + (size_t)r_st[c] * KF + k0 + g_st[c] * 16, &Blds[idx * 16]);
        }
        __syncthreads();
        // fragments: lane covers k = quad*32..quad*32+32 (chunks 2q, 2q+1);
        // identical k-mapping on A and B => gram correct under any shared perm.
        v8i a8[4], b8[4];
#pragma unroll
        for (int mi = 0; mi < 4; ++mi) {
            int rA = wrow + mi * 16 + mrow;
            int4 lo = *(const int4*)&Alds[rA * BKB + ((quad * 2)     ^ (rA & 7)) * 16];
            int4 hi = *(const int4*)&Alds[rA * BKB + ((quad * 2 + 1) ^ (rA & 7)) * 16];
            a8[mi] = (v8i){lo.x, lo.y, lo.z, lo.w, hi.x, hi.y, hi.z, hi.w};
        }
#pragma unroll
        for (int ni = 0; ni < 4; ++ni) {
            int rB = wcol + ni * 16 + mrow;
            int4 lo = *(const int4*)&Blds[rB * BKB + ((quad * 2)     ^ (rB & 7)) * 16];
            int4 hi = *(const int4*)&Blds[rB * BKB + ((quad * 2 + 1) ^ (rB & 7)) * 16];
            b8[ni] = (v8i){lo.x, lo.y, lo.z, lo.w, hi.x, hi.y, hi.z, hi.w};
        }
#pragma unroll
        for (int mi = 0; mi < 4; ++mi)
#pragma unroll
            for (int ni = 0; ni < 4; ++ni)
                acc[mi][ni] = __builtin_amdgcn_mfma_scale_f32_16x16x128_f8f6f4(
                    a8[mi], b8[ni], acc[mi][ni],
                    0, 0,                     // cbsz/blgp = fp8(e4m3)
                    0, 0x7F7F7F7F,            // A scales: E8M0 127 -> 2^0 (exact)
                    0, 0x7F7F7F7F);           // B scales: unit
    }

    unsigned char* outp = partials + (size_t)p * BSZ * BSZ;
#pragma unroll
    for (int mi = 0; mi < 4; ++mi)
#pragma unroll
        for (int ni = 0; ni < 4; ++ni)
#pragma unroll
            for (int r = 0; r < 4; ++r) {
                int row = row0 + wrow + mi * 16 + quad * 4 + r;   // C/D: row=(lane>>4)*4+reg
                int col = col0 + wcol + ni * 16 + mrow;           //      col=lane&15
                int b = __builtin_amdgcn_cvt_pk_fp8_f32(
                            acc[mi][ni][r], acc[mi][ni][r], 0, false);
                outp[(size_t)row * BSZ + col] = (unsigned char)(b & 0xFF);
            }
    if (bi != bj) {
#pragma unroll
        for (int mi = 0; mi < 4; ++mi)
#pragma unroll
            for (int ni = 0; ni < 4; ++ni) {
                int rowm = col0 + wcol + ni * 16 + mrow;
                int colm = row0 + wrow + mi * 16 + quad * 4;   // 4-aligned
                int pk = __builtin_amdgcn_cvt_pk_fp8_f32(
                             acc[mi][ni][0], acc[mi][ni][1], 0, false);
                pk = __builtin_amdgcn_cvt_pk_fp8_f32(
                         acc[mi][ni][2], acc[mi][ni][3], pk, true);
                *(int*)&outp[(size_t)rowm * BSZ + colm] = pk;
            }
    }
}

// K3: per-row loss, single pass. Scores <= 10 analytically (cosine/T), so use
// constant shift 10 (loss is shift-invariant); no srow LDS staging.
__global__ __launch_bounds__(256) void k_loss_rows(
    const unsigned char* __restrict__ partials, const float* __restrict__ inv_norm,
    const int* __restrict__ labels, float* __restrict__ rloss,
    float* __restrict__ rvalid, float* __restrict__ rcorr) {
    int i = blockIdx.x, tid = threadIdx.x;
    __shared__ float red[4];
    float inv_i = inv_norm[i];
    int lab_i = labels[i];

    int j4 = tid * 4;
    float sx = 0.f, sy = 0.f, sz = 0.f, sw = 0.f;
#pragma unroll
    for (int p2 = 0; p2 < SPLITK; ++p2) {
        int v = *(const int*)&partials[(size_t)p2 * BSZ * BSZ + (size_t)i * BSZ + j4];
        sx += __builtin_amdgcn_cvt_f32_fp8(v, 0);
        sy += __builtin_amdgcn_cvt_f32_fp8(v, 1);
        sz += __builtin_amdgcn_cvt_f32_fp8(v, 2);
        sw += __builtin_amdgcn_cvt_f32_fp8(v, 3);
    }
    float4 invj = *(const float4*)&inv_norm[j4];
    float s4[4];
    s4[0] = sx * inv_i * invj.x * TEMP_INV;
    s4[1] = sy * inv_i * invj.y * TEMP_INV;
    s4[2] = sz * inv_i * invj.z * TEMP_INV;
    s4[3] = sw * inv_i * invj.w * TEMP_INV;
    int4 labj = *(const int4*)&labels[j4];
    const int* labjp = &labj.x;

    float pos_sum = 0.f, neg_sum = 0.f, mp = -3.0e38f, mn = -3.0e38f;
#pragma unroll
    for (int q = 0; q < 4; ++q) {
        int j = j4 + q;
        if (j == i) continue;
        float s = s4[q];
        float e = __expf(s - 10.0f);           // s <= 10+eps -> e in (0,~1]
        if (labjp[q] == lab_i) { pos_sum += e; mp = fmaxf(mp, s); }
        else                   { neg_sum += e; mn = fmaxf(mn, s); }
    }
    float ps = blockSum(pos_sum, red, tid);
    float ns = blockSum(neg_sum, red, tid);
    float mpa = blockMax(mp, red, tid);
    float mna = blockMax(mn, red, tid);
    if (tid == 0) {
        bool valid = (mpa > -1.0e37f) && (mna > -1.0e37f);
        rloss[i]  = valid ? (logf(ns) - logf(ps)) : 0.f;
        rvalid[i] = valid ? 1.f : 0.f;
        rcorr[i]  = (valid && (mpa > mna)) ? 1.f : 0.f;
    }
}

// K4: final scalar reduce -> d_out[0]=loss, d_out[1]=accuracy
__global__ __launch_bounds__(256) void k_final(
    const float* __restrict__ rloss, const float* __restrict__ rvalid,
    const float* __restrict__ rcorr, float* __restrict__ out) {
    __shared__ float red[4];
    int tid = threadIdx.x;
    float sl = 0.f, sv = 0.f, sc = 0.f;
    for (int c = 0; c < 4; ++c) {
        int j = c * 256 + tid;
        sl += rloss[j]; sv += rvalid[j]; sc += rcorr[j];
    }
    sl = blockSum(sl, red, tid);
    sv = blockSum(sv, red, tid);
    sc = blockSum(sc, red, tid);
    if (tid == 0) {
        out[0] = (sv > 0.f) ? sl / fmaxf(sv, 1.f) : 0.f;
        out[1] = (sv > 0.f) ? sc / fmaxf(sv, 1.f) : 0.5f;
    }
}

extern "C" void kernel_launch(void* const* d_in, const int* in_sizes, int n_in,
                              void* d_out, int out_size, void* d_ws, size_t ws_size,
                              hipStream_t stream) {
    const float* feats = (const float*)d_in[0];
    const int* labels = (const int*)d_in[1];
    float* out = (float*)d_out;
    char* ws = (char*)d_ws;

    // ws: [0,32MB) fp8 features | [32MB,64MB) 32 fp8 gram partials | small arrays
    unsigned char* f8       = (unsigned char*)ws;
    unsigned char* partials = (unsigned char*)(ws + (size_t)32 * 1024 * 1024);
    float* inv_norm         = (float*)(ws + (size_t)64 * 1024 * 1024);
    float* rloss            = inv_norm + BSZ;
    float* rvalid           = rloss + BSZ;
    float* rcorr            = rvalid + BSZ;

    k_norm_convert<<<BSZ, 256, 0, stream>>>(feats, f8, inv_norm);
    k_gemm<<<dim3(36, SPLITK), 256, 0, stream>>>(f8, partials);
    k_loss_rows<<<BSZ, 256, 0, stream>>>(partials, inv_norm, labels, rloss, rvalid, rcorr);
    k_final<<<1, 256, 0, stream>>>(rloss, rvalid, rcorr, out);
}